// Round 1
// baseline (58.617 us; speedup 1.0000x reference)
//
#include <hip/hip_runtime.h>
#include <hip/hip_bf16.h>
#include <stdint.h>

#define HEIGHT 32
#define WIDTH  8192
#define KDIM   256
#define NDIM   512
#define BM     64

typedef float f32x4  __attribute__((ext_vector_type(4)));
typedef float f32x16 __attribute__((ext_vector_type(16)));
typedef short bf16x8 __attribute__((ext_vector_type(8)));

__device__ __forceinline__ ushort f2bf(float x) {
  union { float f; uint32_t u; } un; un.f = x;
  uint32_t u = un.u;
  u += 0x7FFFu + ((u >> 16) & 1u);   // round-to-nearest-even
  return (ushort)(u >> 16);
}

// lin_w [K=256][N=512] f32  ->  wt [N=512][K=256] bf16 (transposed for MFMA B-frag 16B loads)
__global__ void prep_w_kernel(const float* __restrict__ lin_w, ushort* __restrict__ wt) {
  int idx = blockIdx.x * 256 + threadIdx.x;   // 0..131071
  int k = idx >> 9;                           // contiguous read over n
  int n = idx & 511;
  wt[n * KDIM + k] = f2bf(lin_w[k * NDIM + n]);
}

__global__ __launch_bounds__(512) void fused_kernel(
    const float* __restrict__ images, const float* __restrict__ conv_w,
    const float* __restrict__ conv_b, const ushort* __restrict__ wt,
    const float* __restrict__ lin_b, float* __restrict__ out) {
  __shared__ ushort A[BM * KDIM];   // 32 KB, XOR-swizzled bf16 feats [row=slice][k=h*8+w]

  const int tid = threadIdx.x;
  const int rb  = blockIdx.x;       // 0..1023
  const int b   = rb >> 4;          // batch
  const int s0  = (rb & 15) * BM;   // first slice of this block within batch

  float cw[9];
#pragma unroll
  for (int i = 0; i < 9; ++i) cw[i] = conv_w[i];
  const float cb = conv_b[0];

  // ---------- phase 1: per-slice 3x3 conv + ReLU -> bf16 into LDS ----------
  {
    const int sl = tid & 63;        // local slice (= LDS A row)
    const int hg = tid >> 6;        // 0..7, each owns 4 output h-rows
    const int h0 = hg * 4;
    const float* base = images + (size_t)b * HEIGHT * WIDTH + (size_t)(s0 + sl) * 8;

    float r[6][8];
#pragma unroll
    for (int i = 0; i < 6; ++i) {
      const int h = h0 - 1 + i;
      if (h >= 0 && h < HEIGHT) {
        const f32x4* p = reinterpret_cast<const f32x4*>(base + (size_t)h * WIDTH);
        f32x4 lo = p[0], hi = p[1];
#pragma unroll
        for (int w = 0; w < 4; ++w) { r[i][w] = lo[w]; r[i][4 + w] = hi[w]; }
      } else {
#pragma unroll
        for (int w = 0; w < 8; ++w) r[i][w] = 0.f;
      }
    }

#pragma unroll
    for (int oh = 0; oh < 4; ++oh) {
      float y[8];
#pragma unroll
      for (int w = 0; w < 8; ++w) y[w] = cb;
#pragma unroll
      for (int dh = 0; dh < 3; ++dh) {
#pragma unroll
        for (int dw = 0; dw < 3; ++dw) {
          const float c = cw[dh * 3 + dw];
#pragma unroll
          for (int w = 0; w < 8; ++w) {
            const int iw = w + dw - 1;          // per-slice zero padding in w
            if (iw >= 0 && iw < 8) y[w] = fmaf(r[oh + dh][iw], c, y[w]);
          }
        }
      }
      bf16x8 pack;
#pragma unroll
      for (int w = 0; w < 8; ++w) pack[w] = (short)f2bf(fmaxf(y[w], 0.f));
      int byte = sl * 512 + (h0 + oh) * 16;     // k = (h0+oh)*8 .. +7 (16 bytes)
      byte ^= (sl & 7) << 4;                    // bank-conflict swizzle
      *reinterpret_cast<bf16x8*>(reinterpret_cast<char*>(A) + byte) = pack;
    }
  }
  __syncthreads();

  // ---------- phase 2: [64 x 256] @ [256 x 512] via mfma_32x32x16_bf16 ----------
  const int lane = tid & 63;
  const int wid  = tid >> 6;        // 8 waves, each 64 rows x 64 cols
  const int n0   = wid * 64;
  const int la   = lane & 31;
  const int lb   = lane >> 5;

  f32x16 acc[2][2];
#pragma unroll
  for (int mf = 0; mf < 2; ++mf)
#pragma unroll
    for (int nf = 0; nf < 2; ++nf)
#pragma unroll
      for (int i = 0; i < 16; ++i) acc[mf][nf][i] = 0.f;

  const ushort* wbase = wt + (size_t)(n0 + la) * KDIM + lb * 8;

#pragma unroll
  for (int k0 = 0; k0 < 16; ++k0) {
    bf16x8 af[2], bfr[2];
#pragma unroll
    for (int mf = 0; mf < 2; ++mf) {
      const int row = mf * 32 + la;
      int byte = row * 512 + k0 * 32 + lb * 16;
      byte ^= (row & 7) << 4;
      af[mf] = *reinterpret_cast<const bf16x8*>(reinterpret_cast<const char*>(A) + byte);
    }
#pragma unroll
    for (int nf = 0; nf < 2; ++nf)
      bfr[nf] = *reinterpret_cast<const bf16x8*>(wbase + nf * 32 * KDIM + k0 * 16);
#pragma unroll
    for (int mf = 0; mf < 2; ++mf)
#pragma unroll
      for (int nf = 0; nf < 2; ++nf)
        acc[mf][nf] = __builtin_amdgcn_mfma_f32_32x32x16_bf16(af[mf], bfr[nf], acc[mf][nf], 0, 0, 0);
  }

  // ---------- epilogue: + bias, store fp32 ----------
  const size_t row0 = (size_t)rb * BM;
#pragma unroll
  for (int mf = 0; mf < 2; ++mf) {
#pragma unroll
    for (int nf = 0; nf < 2; ++nf) {
      const int col = n0 + nf * 32 + la;
      const float bias = lin_b[col];
#pragma unroll
      for (int reg = 0; reg < 16; ++reg) {
        const int rr = mf * 32 + (reg & 3) + 8 * (reg >> 2) + 4 * lb;
        out[(row0 + rr) * NDIM + col] = acc[mf][nf][reg] + bias;
      }
    }
  }
}

extern "C" void kernel_launch(void* const* d_in, const int* in_sizes, int n_in,
                              void* d_out, int out_size, void* d_ws, size_t ws_size,
                              hipStream_t stream) {
  const float* images = (const float*)d_in[0];
  const float* conv_w = (const float*)d_in[1];
  const float* conv_b = (const float*)d_in[2];
  const float* lin_w  = (const float*)d_in[3];
  const float* lin_b  = (const float*)d_in[4];
  float* out = (float*)d_out;
  ushort* wt = (ushort*)d_ws;      // 512*256*2 = 256 KB

  hipLaunchKernelGGL(prep_w_kernel, dim3(512), dim3(256), 0, stream, lin_w, wt);
  hipLaunchKernelGGL(fused_kernel, dim3(1024), dim3(512), 0, stream,
                     images, conv_w, conv_b, wt, lin_b, out);
}